// Round 9
// baseline (781.499 us; speedup 1.0000x reference)
//
#include <hip/hip_runtime.h>

// ---------------------------------------------------------------------------
// LUNA fused pipeline for MI355X / gfx950.  B=16, S=4096, P=64, QKV=512, H=8.
// R9: A-DIRECT-TO-REGISTER GEMM: A fragments loaded per-lane from global
//     (fp32 cvt in-register; conv pass stays eliminated), B only in LDS
//     (triple-buffered 24KB, R7's verified conflict-free swizzle), counted
//     vmcnt(2) keeps next B-DMA in flight across barriers.  Halves LDS
//     reads/MFMA and DMA instructions vs R8.
// ---------------------------------------------------------------------------

typedef __bf16 bf16x8 __attribute__((ext_vector_type(8)));
typedef float f32x4 __attribute__((ext_vector_type(4)));
typedef unsigned short u16x8 __attribute__((ext_vector_type(8)));
typedef unsigned short u16x4 __attribute__((ext_vector_type(4)));

#define MFMA16(a, b, c) __builtin_amdgcn_mfma_f32_16x16x32_bf16((a), (b), (c), 0, 0, 0)

__device__ __forceinline__ unsigned short f2bf_bits(float f) {
  unsigned int u = __float_as_uint(f);
  u += 0x7fffu + ((u >> 16) & 1u);  // RTNE (finite inputs)
  return (unsigned short)(u >> 16);
}

__device__ __forceinline__ void gload16(const void* g, void* l) {
  __builtin_amdgcn_global_load_lds(
      (const __attribute__((address_space(1))) void*)g,
      (__attribute__((address_space(3))) void*)l, 16, 0, 0);
}

// ---------------------------------------------------------------------------
// prep: z 0..7 -> transpose+convert W_z into bf16 W^T; z==8 -> combined biases.
// ---------------------------------------------------------------------------
struct Ptr8 { const float* p[8]; };

__global__ __launch_bounds__(256) void prep_kernel(
    Ptr8 srcs, unsigned short* __restrict__ WT,
    const float* bi, const float* bip, const float* bic,
    const float* Wq, const float* Wpq, const float* Wpk, const float* Wpv,
    const float* bq, const float* bpq, const float* bpk, const float* bpv,
    float* __restrict__ bias_out) {
  const int t = threadIdx.x;
  if (blockIdx.z < 8) {
    const float* __restrict__ W = srcs.p[blockIdx.z];
    unsigned short* __restrict__ O = WT + (size_t)blockIdx.z * 262144;
    __shared__ float tile[32][33];
    const int tr = blockIdx.x * 32, tc = blockIdx.y * 32;
    {
      const int r = t >> 3, c4 = (t & 7) * 4;
      const float4 v = *reinterpret_cast<const float4*>(&W[(size_t)(tr + r) * 512 + tc + c4]);
      tile[r][c4 + 0] = v.x; tile[r][c4 + 1] = v.y; tile[r][c4 + 2] = v.z; tile[r][c4 + 3] = v.w;
    }
    __syncthreads();
    {
      const int n = t >> 3, k4 = (t & 7) * 4;
      u16x4 o;
#pragma unroll
      for (int j = 0; j < 4; j++) o[j] = f2bf_bits(tile[k4 + j][n]);
      *reinterpret_cast<u16x4*>(&O[(size_t)(tc + n) * 512 + tr + k4]) = o;
    }
  } else {
    const int idx = blockIdx.y * 16 + blockIdx.x;
    if (idx >= 8) return;
    const int y = idx >> 1;
    const float* bin  = (y == 0) ? bi : (y == 1) ? bip : bic;
    const float* W    = (y == 0) ? Wq : (y == 1) ? Wpq : (y == 2) ? Wpk : Wpv;
    const float* bout = (y == 0) ? bq : (y == 1) ? bpq : (y == 2) ? bpk : bpv;
    const float scale = (y < 2) ? 0.125f : 1.0f;
    const int n = (idx & 1) * 256 + t;
    float s = 0.f;
    for (int k = 0; k < 512; k++) s += bin[k] * W[(size_t)k * 512 + n];
    bias_out[y * 512 + n] = (s + bout[n]) * scale;
  }
}

// ---------------------------------------------------------------------------
// Batched weight-combine: out_z^T = scale_z * (A_z @ WT_z^T), z in 0..3.
// ---------------------------------------------------------------------------
__global__ __launch_bounds__(256) void gemm_wcomb(
    const float* __restrict__ Wi, const float* __restrict__ Wip,
    const float* __restrict__ Wic, const unsigned short* __restrict__ WTbase,
    unsigned short* __restrict__ outbase) {
  const int z = blockIdx.z;
  const float* __restrict__ A = (z == 0) ? Wi : (z == 1) ? Wip : Wic;
  const unsigned short* __restrict__ BT = WTbase + (size_t)z * 262144;
  unsigned short* __restrict__ out = outbase + (size_t)z * 262144;
  const float scale = (z < 2) ? 0.125f : 1.0f;

  __shared__ __align__(16) unsigned short As[128 * 72];
  __shared__ __align__(16) unsigned short Bs[128 * 72];
  const int t = threadIdx.x;
  const int w = t >> 6, l = t & 63, li = l & 15, lg = l >> 4;
  const int wm = w >> 1, wn = w & 1;
  const int m0 = blockIdx.x * 128, n0 = blockIdx.y * 128;

  f32x4 acc[4][4] = {};

  for (int kt = 0; kt < 512; kt += 64) {
#pragma unroll
    for (int i = 0; i < 8; i++) {
      const int row = i * 16 + (t >> 4), k = (t & 15) * 4;
      const float4 v = *reinterpret_cast<const float4*>(&A[(size_t)(m0 + row) * 512 + kt + k]);
      u16x4 o;
      o[0] = f2bf_bits(v.x); o[1] = f2bf_bits(v.y);
      o[2] = f2bf_bits(v.z); o[3] = f2bf_bits(v.w);
      *reinterpret_cast<u16x4*>(&As[row * 72 + k]) = o;
    }
#pragma unroll
    for (int i = 0; i < 4; i++) {
      const int row = i * 32 + (t >> 3), k = (t & 7) * 8;
      const u16x8 v = *reinterpret_cast<const u16x8*>(&BT[(size_t)(n0 + row) * 512 + kt + k]);
      *reinterpret_cast<u16x8*>(&Bs[row * 72 + k]) = v;
    }
    __syncthreads();
#pragma unroll
    for (int kk = 0; kk < 2; kk++) {
      bf16x8 a[4], b[4];
#pragma unroll
      for (int mf = 0; mf < 4; mf++)
        a[mf] = *reinterpret_cast<const bf16x8*>(&As[(wm * 64 + mf * 16 + li) * 72 + kk * 32 + lg * 8]);
#pragma unroll
      for (int nf = 0; nf < 4; nf++)
        b[nf] = *reinterpret_cast<const bf16x8*>(&Bs[(wn * 64 + nf * 16 + li) * 72 + kk * 32 + lg * 8]);
#pragma unroll
      for (int mf = 0; mf < 4; mf++)
#pragma unroll
        for (int nf = 0; nf < 4; nf++)
          acc[mf][nf] = MFMA16(a[mf], b[nf], acc[mf][nf]);
    }
    __syncthreads();
  }
  const int lg4 = lg * 4;
#pragma unroll
  for (int nf = 0; nf < 4; nf++) {
    const int col = n0 + wn * 64 + nf * 16 + li;
#pragma unroll
    for (int mf = 0; mf < 4; mf++) {
      const int row = m0 + wm * 64 + mf * 16 + lg4;
#pragma unroll
      for (int r = 0; r < 4; r++)
        out[(size_t)col * 512 + row + r] = f2bf_bits(acc[mf][nf][r] * scale);
    }
  }
}

// ---------------------------------------------------------------------------
// Pipeline sync macros.
// ---------------------------------------------------------------------------
#define WAITV(n)                                            \
  {                                                         \
    asm volatile("s_waitcnt vmcnt(" #n ")" ::: "memory");   \
    __builtin_amdgcn_sched_barrier(0);                      \
  }
#define BAR3()                                              \
  {                                                         \
    __builtin_amdgcn_s_barrier();                           \
    __builtin_amdgcn_sched_barrier(0);                      \
  }

// ---------------------------------------------------------------------------
// gemm_areg_body: A fragments DIRECT from global into registers (fp32 cvt'd
// in-register, or bf16 bitcast).  B via global_load_lds, triple-buffered
// (24KB LDS), counted vmcnt(2).  128x128 tile, BK=32, K=512 (16 steps).
// Per iter: WAITV(2) [A(t) regs + B(t) LDS landed; B(t+1) DMA stays in
// flight across the barrier] -> cvt -> issue A(t+1), B(t+2) -> BAR ->
// 4 ds_read + 16 MFMA -> BAR.
// ---------------------------------------------------------------------------
template <int AF32, int OUTF32>
__device__ __forceinline__ void gemm_areg_body(
    const void* __restrict__ Av, const unsigned short* __restrict__ BT,
    const float* __restrict__ bias, void* out, int Ntiles, int ldc, int wg) {
  __shared__ __align__(16) unsigned short Bs[3][128 * 32];  // 24 KB
  const int t = threadIdx.x;
  const int w = t >> 6, l = t & 63, li = l & 15, lg = l >> 4;
  const int wm = w >> 1, wn = w & 1;
  const int m0 = (wg / Ntiles) * 128, n0 = (wg % Ntiles) * 128;

  f32x4 acc[4][4] = {};
  float4 rawA[4][2];
  u16x8 rawH[4];
  bf16x8 af[4];
  const int brow_ = t >> 2, bslot_ = t & 3;

  const float* apf = (const float*)Av + (size_t)(m0 + wm * 64 + li) * 512 + lg * 8;
  const unsigned short* aph =
      (const unsigned short*)Av + (size_t)(m0 + wm * 64 + li) * 512 + lg * 8;

#define STAGE_B(tile)                                                          \
  {                                                                            \
    const int bb = (tile) % 3;                                                 \
    const int kt = (tile) * 32;                                                \
    _Pragma("unroll") for (int i = 0; i < 2; i++) {                            \
      const int row = i * 64 + brow_;                                          \
      const int gs = (bslot_ ^ ((row >> 1) & 3)) * 8;                          \
      gload16(&BT[(size_t)(n0 + row) * 512 + kt + gs],                         \
              &Bs[bb][(i * 256 + t) * 8]);                                     \
    }                                                                          \
  }

#define ISSUE_A(kt)                                                            \
  if constexpr (AF32) {                                                        \
    _Pragma("unroll") for (int mf = 0; mf < 4; mf++) {                         \
      rawA[mf][0] = *reinterpret_cast<const float4*>(apf + (size_t)mf * 8192 + (kt)); \
      rawA[mf][1] = *reinterpret_cast<const float4*>(apf + (size_t)mf * 8192 + (kt) + 4); \
    }                                                                          \
  } else {                                                                     \
    _Pragma("unroll") for (int mf = 0; mf < 4; mf++)                           \
        rawH[mf] = *reinterpret_cast<const u16x8*>(aph + (size_t)mf * 8192 + (kt)); \
  }

#define CVT_A()                                                                \
  if constexpr (AF32) {                                                        \
    _Pragma("unroll") for (int mf = 0; mf < 4; mf++) {                         \
      bf16x8 v;                                                                \
      _Pragma("unroll") for (int j = 0; j < 4; j++) {                          \
        v[j] = (__bf16)rawA[mf][0][j];                                         \
        v[j + 4] = (__bf16)rawA[mf][1][j];                                     \
      }                                                                        \
      af[mf] = v;                                                              \
    }                                                                          \
  } else {                                                                     \
    _Pragma("unroll") for (int mf = 0; mf < 4; mf++)                           \
        af[mf] = *reinterpret_cast<const bf16x8*>(&rawH[mf]);                  \
  }

#define COMPUTE(tile)                                                          \
  {                                                                            \
    const int bb = (tile) % 3;                                                 \
    bf16x8 bfr[4];                                                             \
    _Pragma("unroll") for (int nf = 0; nf < 4; nf++) {                         \
      const int r = wn * 64 + nf * 16 + li;                                    \
      bfr[nf] = *reinterpret_cast<const bf16x8*>(                              \
          &Bs[bb][r * 32 + ((lg ^ ((r >> 1) & 3)) * 8)]);                      \
    }                                                                          \
    _Pragma("unroll") for (int mf = 0; mf < 4; mf++)                           \
        _Pragma("unroll") for (int nf = 0; nf < 4; nf++)                       \
            acc[mf][nf] = MFMA16(af[mf], bfr[nf], acc[mf][nf]);                \
  }

  // prologue: A(0) regs + B(0), B(1) DMA in flight
  ISSUE_A(0);
  STAGE_B(0);
  STAGE_B(1);

#pragma unroll 1
  for (int tt = 0; tt < 15; ++tt) {
    WAITV(2);            // A(tt) + B(tt) landed; B(tt+1) stays in flight
    CVT_A();             // consume raw regs
    ISSUE_A((tt + 1) * 32);        // re-arm raw regs (covered by compute)
    if (tt < 14) STAGE_B(tt + 2);  // covered by this whole iter + next
    BAR3();              // all waves' B(tt) DMA drained
    COMPUTE(tt);
    BAR3();              // buf[tt%3] free for re-arm next iter
  }
  // peel tt=15
  WAITV(0);
  CVT_A();
  BAR3();
  COMPUTE(15);

#undef STAGE_B
#undef ISSUE_A
#undef CVT_A
#undef COMPUTE

  const int lg4 = lg * 4;
#pragma unroll
  for (int nf = 0; nf < 4; nf++) {
    const int col = n0 + wn * 64 + nf * 16 + li;
    const float bv = bias[col];
#pragma unroll
    for (int mf = 0; mf < 4; mf++) {
      const int row = m0 + wm * 64 + mf * 16 + lg4;
      if constexpr (OUTF32) {
        float* o = (float*)out;
#pragma unroll
        for (int r = 0; r < 4; r++)
          o[(size_t)(row + r) * ldc + col] = acc[mf][nf][r] + bv;
      } else {
        unsigned short* o = (unsigned short*)out;
#pragma unroll
        for (int r = 0; r < 4; r++)
          o[(size_t)(row + r) * ldc + col] = f2bf_bits(acc[mf][nf][r] + bv);
      }
    }
  }
}

// Merged q + pkv + pq projections (fp32 A).  grid 6176 (2048 q | 4096 pkv | 32 pq).
__global__ __launch_bounds__(256, 3) void gemm_areg_qpkv(
    const float* query, const float* context, const float* pquery,
    const unsigned short* WqeT, const unsigned short* WpkveT,
    const unsigned short* WpqeT, const float* bqe, const float* bpkve,
    const float* bpqe, unsigned short* q_buf, unsigned short* pkv_buf,
    unsigned short* pq_buf) {
  const int q8 = gridDim.x >> 3;
  int wg = ((int)blockIdx.x & 7) * q8 + ((int)blockIdx.x >> 3);
  const float* A;
  const unsigned short* BT;
  const float* bias;
  unsigned short* out;
  int Ntiles, ldc;
  if (wg < 2048) {
    A = query; BT = WqeT; bias = bqe; out = q_buf; Ntiles = 4; ldc = 512;
  } else if (wg < 6144) {
    wg -= 2048; A = context; BT = WpkveT; bias = bpkve; out = pkv_buf;
    Ntiles = 8; ldc = 1024;
  } else {
    wg -= 6144; A = pquery; BT = WpqeT; bias = bpqe; out = pq_buf;
    Ntiles = 4; ldc = 512;
  }
  gemm_areg_body<1, 0>(A, BT, bias, out, Ntiles, ldc, wg);
}

// Final projection: attn = attn_h @ Wo + bo (bf16 A, fp32 out).  grid 2048.
__global__ __launch_bounds__(256, 3) void gemm_areg_final(
    const unsigned short* A, const unsigned short* BT, const float* bias,
    float* out) {
  const int q8 = gridDim.x >> 3;
  const int wg = ((int)blockIdx.x & 7) * q8 + ((int)blockIdx.x >> 3);
  gemm_areg_body<0, 1>(A, BT, bias, out, 4, 512, wg);
}

// ---------------------------------------------------------------------------
// 128x128 bf16 GEMM (1-phase) for the small kv/pc GEMM, N=1536 split output.
// ---------------------------------------------------------------------------
__global__ __launch_bounds__(256) void gemm_kvpc(
    const unsigned short* __restrict__ A, const unsigned short* __restrict__ BT,
    const float* __restrict__ bias0, const float* __restrict__ bias1,
    const float* __restrict__ bias2, unsigned short* out0, unsigned short* out1,
    float* out2, int Ntiles) {
  __shared__ __align__(16) unsigned short As[128 * 64];
  __shared__ __align__(16) unsigned short Bs[128 * 64];
  const int t = threadIdx.x;
  const int w = t >> 6, l = t & 63, li = l & 15, lg = l >> 4;
  const int wm = w >> 1, wn = w & 1;
  const int K = 512;
  const int m0 = (blockIdx.x / Ntiles) * 128, n0 = (blockIdx.x % Ntiles) * 128;

  f32x4 acc[4][4] = {};
  const int sr = t >> 3, sslot = t & 7;

  for (int kt = 0; kt < K; kt += 64) {
#pragma unroll
    for (int i = 0; i < 4; i++) {
      const int row = i * 32 + sr;
      const int gs = (sslot ^ (row & 7)) * 8;
      gload16(&A[(size_t)(m0 + row) * K + kt + gs], &As[(i * 256 + t) * 8]);
      gload16(&BT[(size_t)(n0 + row) * K + kt + gs], &Bs[(i * 256 + t) * 8]);
    }
    __syncthreads();
#pragma unroll
    for (int kk = 0; kk < 2; kk++) {
      bf16x8 a[4], b[4];
#pragma unroll
      for (int mf = 0; mf < 4; mf++) {
        const int r = wm * 64 + mf * 16 + li;
        a[mf] = *reinterpret_cast<const bf16x8*>(&As[r * 64 + (((kk * 4 + lg) ^ (r & 7)) * 8)]);
      }
#pragma unroll
      for (int nf = 0; nf < 4; nf++) {
        const int r = wn * 64 + nf * 16 + li;
        b[nf] = *reinterpret_cast<const bf16x8*>(&Bs[r * 64 + (((kk * 4 + lg) ^ (r & 7)) * 8)]);
      }
#pragma unroll
      for (int mf = 0; mf < 4; mf++)
#pragma unroll
        for (int nf = 0; nf < 4; nf++)
          acc[mf][nf] = MFMA16(a[mf], b[nf], acc[mf][nf]);
    }
    __syncthreads();
  }

  const int lg4 = lg * 4;
#pragma unroll
  for (int nf = 0; nf < 4; nf++) {
    const int col = n0 + wn * 64 + nf * 16 + li;
    if (col < 512) {
      const float bv = bias0[col];
#pragma unroll
      for (int mf = 0; mf < 4; mf++) {
        const int row = m0 + wm * 64 + mf * 16 + lg4;
#pragma unroll
        for (int r = 0; r < 4; r++)
          out0[(size_t)(row + r) * 512 + col] = f2bf_bits(acc[mf][nf][r] + bv);
      }
    } else if (col < 1024) {
      const float bv = bias1[col - 512];
#pragma unroll
      for (int mf = 0; mf < 4; mf++) {
        const int row = m0 + wm * 64 + mf * 16 + lg4;
#pragma unroll
        for (int r = 0; r < 4; r++)
          out1[(size_t)(row + r) * 512 + col - 512] = f2bf_bits(acc[mf][nf][r] + bv);
      }
    } else {
      const float bv = bias2[col - 1024];
#pragma unroll
      for (int mf = 0; mf < 4; mf++) {
        const int row = m0 + wm * 64 + mf * 16 + lg4;
#pragma unroll
        for (int r = 0; r < 4; r++)
          out2[(size_t)(row + r) * 512 + col - 1024] = acc[mf][nf][r] + bv;
      }
    }
  }
}

// ---------------------------------------------------------------------------
// Pack attention, split over S. grid (128 bh, 8 chunks), block 256 (4 waves).
// ---------------------------------------------------------------------------
__global__ __launch_bounds__(256) void pack_attn(
    const unsigned short* __restrict__ pq_buf,
    const unsigned short* __restrict__ pkv_buf, float* __restrict__ partial) {
  __shared__ __align__(16) unsigned short pkL[64 * 72];
  __shared__ __align__(16) unsigned short pvT[64 * 72];
  __shared__ __align__(16) unsigned short prL[4 * 16 * 72];
  const int t = threadIdx.x, w = t >> 6, l = t & 63, li = l & 15, lg = l >> 4;
  const int bh = blockIdx.x, b = bh >> 3, h = bh & 7;
  const int sb = blockIdx.y * 512;

  bf16x8 aq[2];
  {
    const size_t base = ((size_t)(b * 64 + w * 16 + li)) * 512 + h * 64;
    aq[0] = *reinterpret_cast<const bf16x8*>(&pq_buf[base + lg * 8]);
    aq[1] = *reinterpret_cast<const bf16x8*>(&pq_buf[base + 32 + lg * 8]);
  }

  f32x4 acc[4] = {};
  float lsum[4] = {};

  for (int st = 0; st < 8; st++) {
    const int s0 = sb + st * 64;
#pragma unroll
    for (int i = 0; i < 2; i++) {
      const int row = i * 32 + (t >> 3), c = (t & 7) * 8;
      const u16x8 v = *reinterpret_cast<const u16x8*>(
          &pkv_buf[((size_t)(b * 4096 + s0 + row)) * 1024 + h * 64 + c]);
      *reinterpret_cast<u16x8*>(&pkL[row * 72 + c]) = v;
    }
    {
      const int rp = t >> 3, c = (t & 7) * 8;
      const size_t base = ((size_t)(b * 4096 + s0 + 2 * rp)) * 1024 + 512 + h * 64 + c;
      const u16x8 u0 = *reinterpret_cast<const u16x8*>(&pkv_buf[base]);
      const u16x8 u1 = *reinterpret_cast<const u16x8*>(&pkv_buf[base + 1024]);
#pragma unroll
      for (int j = 0; j < 8; j++) {
        const int val = ((int)u0[j] & 0xffff) | ((int)u1[j] << 16);
        *reinterpret_cast<int*>(&pvT[(c + j) * 72 + 2 * rp]) = val;
      }
    }
    __syncthreads();
    f32x4 sc[4] = {};
#pragma unroll
    for (int nf = 0; nf < 4; nf++) {
#pragma unroll
      for (int kk = 0; kk < 2; kk++) {
        const bf16x8 bk = *reinterpret_cast<const bf16x8*>(
            &pkL[(nf * 16 + li) * 72 + kk * 32 + lg * 8]);
        sc[nf] = MFMA16(aq[kk], bk, sc[nf]);
      }
    }
#pragma unroll
    for (int nf = 0; nf < 4; nf++) {
#pragma unroll
      for (int r = 0; r < 4; r++) {
        const float e = __expf(sc[nf][r]);
        lsum[r] += e;
        prL[(w * 16 + lg * 4 + r) * 72 + nf * 16 + li] = f2bf_bits(e);
      }
    }
#pragma unroll
    for (int kk = 0; kk < 2; kk++) {
      const bf16x8 ap = *reinterpret_cast<const bf16x8*>(
          &prL[(w * 16 + li) * 72 + kk * 32 + lg * 8]);
#pragma unroll
      for (int nf = 0; nf < 4; nf++) {
        const bf16x8 bv = *reinterpret_cast<const bf16x8*>(
            &pvT[(nf * 16 + li) * 72 + kk * 32 + lg * 8]);
        acc[nf] = MFMA16(ap, bv, acc[nf]);
      }
    }
    __syncthreads();
  }

#pragma unroll
  for (int m = 1; m < 16; m <<= 1)
#pragma unroll
    for (int r = 0; r < 4; r++) lsum[r] += __shfl_xor(lsum[r], m);

  const size_t pbase = ((size_t)(bh * 8 + blockIdx.y)) * 4160;
#pragma unroll
  for (int nf = 0; nf < 4; nf++)
#pragma unroll
    for (int r = 0; r < 4; r++)
      partial[pbase + (size_t)(w * 16 + lg * 4 + r) * 64 + nf * 16 + li] = acc[nf][r];
  if (li == 0)
#pragma unroll
    for (int r = 0; r < 4; r++) partial[pbase + 4096 + w * 16 + lg * 4 + r] = lsum[r];
}

__global__ __launch_bounds__(256) void pack_combine(const float* __restrict__ partial,
                                                    unsigned short* __restrict__ pc_buf) {
  const int bh = blockIdx.x, b = bh >> 3, h = bh & 7;
  const int t = threadIdx.x;
#pragma unroll
  for (int e = 0; e < 16; e++) {
    const int idx = e * 256 + t;
    const int p = idx >> 6, d = idx & 63;
    float s = 0.f, den = 0.f;
#pragma unroll
    for (int c = 0; c < 8; c++) {
      const float* pb = &partial[((size_t)(bh * 8 + c)) * 4160];
      s += pb[idx];
      den += pb[4096 + p];
    }
    pc_buf[((size_t)(b * 64 + p)) * 512 + h * 64 + d] = f2bf_bits(s / den);
  }
}

// ---------------------------------------------------------------------------
// Unpack attention. grid (16 s-tiles, 128 bh), block 256 (4 waves x 64 s-rows).
// ---------------------------------------------------------------------------
__global__ __launch_bounds__(256) void unpack_attn(
    const unsigned short* q_in, const unsigned short* __restrict__ k_buf,
    const unsigned short* __restrict__ v_buf, float* __restrict__ aw_out,
    unsigned short* attnh_out) {
  __shared__ __align__(16) unsigned short kL[64 * 72];
  __shared__ __align__(16) unsigned short vT[64 * 72];
  __shared__ __align__(16) unsigned short prL[4 * 64 * 72];
  const int t = threadIdx.x, w = t >> 6, l = t & 63, li = l & 15, lg = l >> 4;
  const int bh = blockIdx.y, b = bh >> 3, h = bh & 7;
  const int sbase = blockIdx.x * 256 + w * 64;

#pragma unroll
  for (int i = 0; i < 2; i++) {
    const int p = i * 32 + (t >> 3), c = (t & 7) * 8;
    const u16x8 v = *reinterpret_cast<const u16x8*>(
        &k_buf[((size_t)(b * 64 + p)) * 512 + h * 64 + c]);
    *reinterpret_cast<u16x8*>(&kL[p * 72 + c]) = v;
  }
  {
    const int rp = t >> 3, c = (t & 7) * 8;
    const size_t base = ((size_t)(b * 64 + 2 * rp)) * 512 + h * 64 + c;
    const u16x8 u0 = *reinterpret_cast<const u16x8*>(&v_buf[base]);
    const u16x8 u1 = *reinterpret_cast<const u16x8*>(&v_buf[base + 512]);
#pragma unroll
    for (int j = 0; j < 8; j++) {
      const int val = ((int)u0[j] & 0xffff) | ((int)u1[j] << 16);
      *reinterpret_cast<int*>(&vT[(c + j) * 72 + 2 * rp]) = val;
    }
  }
  bf16x8 aq[4][2];
#pragma unroll
  for (int mf = 0; mf < 4; mf++) {
    const size_t base = ((size_t)(b * 4096 + sbase + mf * 16 + li)) * 512 + h * 64;
    aq[mf][0] = *reinterpret_cast<const bf16x8*>(&q_in[base + lg * 8]);
    aq[mf][1] = *reinterpret_cast<const bf16x8*>(&q_in[base + 32 + lg * 8]);
  }
  __syncthreads();

  f32x4 sc[4][4] = {};
#pragma unroll
  for (int kk = 0; kk < 2; kk++)
#pragma unroll
    for (int nf = 0; nf < 4; nf++) {
      const bf16x8 bk = *reinterpret_cast<const bf16x8*>(
          &kL[(nf * 16 + li) * 72 + kk * 32 + lg * 8]);
#pragma unroll
      for (int mf = 0; mf < 4; mf++) sc[mf][nf] = MFMA16(aq[mf][kk], bk, sc[mf][nf]);
    }

#pragma unroll
  for (int mf = 0; mf < 4; mf++) {
#pragma unroll
    for (int r = 0; r < 4; r++) {
      float e[4];
      float rs = 0.f;
#pragma unroll
      for (int nf = 0; nf < 4; nf++) {
        e[nf] = __expf(sc[mf][nf][r]);
        rs += e[nf];
      }
#pragma unroll
      for (int m = 1; m < 16; m <<= 1) rs += __shfl_xor(rs, m);
      const float inv = 1.0f / rs;
      const int srow = sbase + mf * 16 + lg * 4 + r;
#pragma unroll
      for (int nf = 0; nf < 4; nf++) {
        const float pr = e[nf] * inv;
        aw_out[(size_t)srow * 8192 + bh * 64 + nf * 16 + li] = pr;
        prL[(w * 64 + mf * 16 + lg * 4 + r) * 72 + nf * 16 + li] = f2bf_bits(pr);
      }
    }
  }

  f32x4 acc[4][4] = {};
#pragma unroll
  for (int kk = 0; kk < 2; kk++)
#pragma unroll
    for (int mf = 0; mf < 4; mf++) {
      const bf16x8 ap = *reinterpret_cast<const bf16x8*>(
          &prL[(w * 64 + mf * 16 + li) * 72 + kk * 32 + lg * 8]);
#pragma unroll
      for (int nf = 0; nf < 4; nf++) {
        const bf16x8 bv = *reinterpret_cast<const bf16x8*>(
            &vT[(nf * 16 + li) * 72 + kk * 32 + lg * 8]);
        acc[mf][nf] = MFMA16(ap, bv, acc[mf][nf]);
      }
    }
#pragma unroll
  for (int mf = 0; mf < 4; mf++)
#pragma unroll
    for (int nf = 0; nf < 4; nf++)
#pragma unroll
      for (int r = 0; r < 4; r++)
        attnh_out[((size_t)(b * 4096 + sbase + mf * 16 + lg * 4 + r)) * 512 + h * 64 +
                  nf * 16 + li] = f2bf_bits(acc[mf][nf][r]);
}

// ---------------------------------------------------------------------------
extern "C" void kernel_launch(void* const* d_in, const int* in_sizes, int n_in,
                              void* d_out, int out_size, void* d_ws, size_t ws_size,
                              hipStream_t stream) {
  (void)in_sizes; (void)n_in; (void)out_size; (void)ws_size;

  const float* query   = (const float*)d_in[0];
  const float* pquery  = (const float*)d_in[1];
  const float* context = (const float*)d_in[2];
  const float* Wi  = (const float*)d_in[3];  const float* bi  = (const float*)d_in[4];
  const float* Wip = (const float*)d_in[5];  const float* bip = (const float*)d_in[6];
  const float* Wic = (const float*)d_in[7];  const float* bic = (const float*)d_in[8];
  const float* Wq  = (const float*)d_in[9];  const float* bq  = (const float*)d_in[10];
  const float* Wpq = (const float*)d_in[11]; const float* bpq = (const float*)d_in[12];
  const float* Wk  = (const float*)d_in[13]; const float* bk  = (const float*)d_in[14];
  const float* Wpk = (const float*)d_in[15]; const float* bpk = (const float*)d_in[16];
  const float* Wv  = (const float*)d_in[17]; const float* bv  = (const float*)d_in[18];
  const float* Wpv = (const float*)d_in[19]; const float* bpv = (const float*)d_in[20];
  const float* Wo  = (const float*)d_in[21]; const float* bo  = (const float*)d_in[22];
  const float* Wop = (const float*)d_in[23]; const float* bop = (const float*)d_in[24];

  // ---- workspace layout ----
  char* ws = (char*)d_ws;
  unsigned short* WT     = (unsigned short*)(ws);                 // 8 x 512x512 bf16
  unsigned short* WqeT   = (unsigned short*)(ws + 4u * 1024 * 1024);
  unsigned short* WpqeT  = WqeT + 512 * 512;
  unsigned short* WpkveT = WpqeT + 512 * 512;                     // 1024 x 512
  float* bqe   = (float*)(WpkveT + (size_t)1024 * 512);
  float* bpqe  = bqe + 512;
  float* bpkve = bpqe + 512;
  unsigned short* q_buf   = (unsigned short*)(ws + 8u * 1024 * 1024);  // 65536x512 (later attn_h)
  unsigned short* pkv_buf = q_buf + (size_t)65536 * 512;               // 65536x1024
  unsigned short* pq_buf  = pkv_buf + (size_t)65536 * 1024;
  unsigned short* pc_buf  = pq_buf + (size_t)1024 * 512;
  unsigned short* k_buf   = pc_buf + (size_t)1024 * 512;
  unsigned short* v_buf   = k_buf + (size_t)1024 * 512;
  float* partial = (float*)(v_buf + (size_t)1024 * 512);               // 1024 x 4160 f32

  float* out_attn = (float*)d_out;                       // (B,S,512) fp32
  float* out_pc   = out_attn + (size_t)16 * 4096 * 512;  // (B,P,512)
  float* out_aw   = out_pc + (size_t)16 * 64 * 512;      // (S,B*H,P)

  const dim3 blk(256);

  // 1) weight prep
  Ptr8 tsrc; tsrc.p[0]=Wq; tsrc.p[1]=Wpq; tsrc.p[2]=Wpk; tsrc.p[3]=Wpv;
  tsrc.p[4]=Wk; tsrc.p[5]=Wv; tsrc.p[6]=Wop; tsrc.p[7]=Wo;
  prep_kernel<<<dim3(16, 16, 9), blk, 0, stream>>>(
      tsrc, WT, bi, bip, bic, Wq, Wpq, Wpk, Wpv, bq, bpq, bpk, bpv, bqe);
  gemm_wcomb<<<dim3(4, 4, 4), blk, 0, stream>>>(Wi, Wip, Wic, WT, WqeT);

  // 2) all input projections in ONE launch, A direct-to-register
  gemm_areg_qpkv<<<dim3(6176), blk, 0, stream>>>(
      query, context, pquery, WqeT, WpkveT, WpqeT, bqe, bpkve, bpqe,
      q_buf, pkv_buf, pq_buf);

  // 3) pack attention (8 chunks) + combine -> pc
  pack_attn<<<dim3(128, 8), blk, 0, stream>>>(pq_buf, pkv_buf, partial);
  pack_combine<<<128, blk, 0, stream>>>(partial, pc_buf);

  // 4) k, v, pc_out (fused N=1536)
  gemm_kvpc<<<dim3(96), blk, 0, stream>>>(
      pc_buf, WT + (size_t)4 * 262144, bk, bv, bop, k_buf, v_buf, out_pc, 12);

  // 5) unpack attention: aw_t out + attn_h in-place over q_buf
  unpack_attn<<<dim3(16, 128), blk, 0, stream>>>(q_buf, k_buf, v_buf, out_aw, q_buf);

  // 6) final projection: attn = attn_h @ Wo + bo (bf16 A direct-to-register)
  gemm_areg_final<<<dim3(2048), blk, 0, stream>>>(
      q_buf, WT + (size_t)7 * 262144, bo, out_attn);
}

// Round 10
// 507.328 us; speedup vs baseline: 1.5404x; 1.5404x over previous
//
#include <hip/hip_runtime.h>

// ---------------------------------------------------------------------------
// LUNA fused pipeline for MI355X / gfx950.  B=16, S=4096, P=64, QKV=512, H=8.
// R10: merged projection GEMM = R7's all-DMA counted pipeline for B (depth-2,
//      triple-buffered) + fp32 A ingested via regs->cvt->lane-linear
//      ds_write_b128 into R7's exact LDS image (proven 0-conflict read).
//      Deterministic issue order keeps vmcnt counts exact.  40KB LDS,
//      4 blocks/CU.  Conv pass stays eliminated.
// ---------------------------------------------------------------------------

typedef __bf16 bf16x8 __attribute__((ext_vector_type(8)));
typedef float f32x4 __attribute__((ext_vector_type(4)));
typedef unsigned short u16x8 __attribute__((ext_vector_type(8)));
typedef unsigned short u16x4 __attribute__((ext_vector_type(4)));

#define MFMA16(a, b, c) __builtin_amdgcn_mfma_f32_16x16x32_bf16((a), (b), (c), 0, 0, 0)

__device__ __forceinline__ unsigned short f2bf_bits(float f) {
  unsigned int u = __float_as_uint(f);
  u += 0x7fffu + ((u >> 16) & 1u);  // RTNE (finite inputs)
  return (unsigned short)(u >> 16);
}

__device__ __forceinline__ void gload16(const void* g, void* l) {
  __builtin_amdgcn_global_load_lds(
      (const __attribute__((address_space(1))) void*)g,
      (__attribute__((address_space(3))) void*)l, 16, 0, 0);
}

// ---------------------------------------------------------------------------
// prep: z 0..7 -> transpose+convert W_z into bf16 W^T; z==8 -> combined biases.
// ---------------------------------------------------------------------------
struct Ptr8 { const float* p[8]; };

__global__ __launch_bounds__(256) void prep_kernel(
    Ptr8 srcs, unsigned short* __restrict__ WT,
    const float* bi, const float* bip, const float* bic,
    const float* Wq, const float* Wpq, const float* Wpk, const float* Wpv,
    const float* bq, const float* bpq, const float* bpk, const float* bpv,
    float* __restrict__ bias_out) {
  const int t = threadIdx.x;
  if (blockIdx.z < 8) {
    const float* __restrict__ W = srcs.p[blockIdx.z];
    unsigned short* __restrict__ O = WT + (size_t)blockIdx.z * 262144;
    __shared__ float tile[32][33];
    const int tr = blockIdx.x * 32, tc = blockIdx.y * 32;
    {
      const int r = t >> 3, c4 = (t & 7) * 4;
      const float4 v = *reinterpret_cast<const float4*>(&W[(size_t)(tr + r) * 512 + tc + c4]);
      tile[r][c4 + 0] = v.x; tile[r][c4 + 1] = v.y; tile[r][c4 + 2] = v.z; tile[r][c4 + 3] = v.w;
    }
    __syncthreads();
    {
      const int n = t >> 3, k4 = (t & 7) * 4;
      u16x4 o;
#pragma unroll
      for (int j = 0; j < 4; j++) o[j] = f2bf_bits(tile[k4 + j][n]);
      *reinterpret_cast<u16x4*>(&O[(size_t)(tc + n) * 512 + tr + k4]) = o;
    }
  } else {
    const int idx = blockIdx.y * 16 + blockIdx.x;
    if (idx >= 8) return;
    const int y = idx >> 1;
    const float* bin  = (y == 0) ? bi : (y == 1) ? bip : bic;
    const float* W    = (y == 0) ? Wq : (y == 1) ? Wpq : (y == 2) ? Wpk : Wpv;
    const float* bout = (y == 0) ? bq : (y == 1) ? bpq : (y == 2) ? bpk : bpv;
    const float scale = (y < 2) ? 0.125f : 1.0f;
    const int n = (idx & 1) * 256 + t;
    float s = 0.f;
    for (int k = 0; k < 512; k++) s += bin[k] * W[(size_t)k * 512 + n];
    bias_out[y * 512 + n] = (s + bout[n]) * scale;
  }
}

// ---------------------------------------------------------------------------
// Batched weight-combine: out_z^T = scale_z * (A_z @ WT_z^T), z in 0..3.
// ---------------------------------------------------------------------------
__global__ __launch_bounds__(256) void gemm_wcomb(
    const float* __restrict__ Wi, const float* __restrict__ Wip,
    const float* __restrict__ Wic, const unsigned short* __restrict__ WTbase,
    unsigned short* __restrict__ outbase) {
  const int z = blockIdx.z;
  const float* __restrict__ A = (z == 0) ? Wi : (z == 1) ? Wip : Wic;
  const unsigned short* __restrict__ BT = WTbase + (size_t)z * 262144;
  unsigned short* __restrict__ out = outbase + (size_t)z * 262144;
  const float scale = (z < 2) ? 0.125f : 1.0f;

  __shared__ __align__(16) unsigned short As[128 * 72];
  __shared__ __align__(16) unsigned short Bs[128 * 72];
  const int t = threadIdx.x;
  const int w = t >> 6, l = t & 63, li = l & 15, lg = l >> 4;
  const int wm = w >> 1, wn = w & 1;
  const int m0 = blockIdx.x * 128, n0 = blockIdx.y * 128;

  f32x4 acc[4][4] = {};

  for (int kt = 0; kt < 512; kt += 64) {
#pragma unroll
    for (int i = 0; i < 8; i++) {
      const int row = i * 16 + (t >> 4), k = (t & 15) * 4;
      const float4 v = *reinterpret_cast<const float4*>(&A[(size_t)(m0 + row) * 512 + kt + k]);
      u16x4 o;
      o[0] = f2bf_bits(v.x); o[1] = f2bf_bits(v.y);
      o[2] = f2bf_bits(v.z); o[3] = f2bf_bits(v.w);
      *reinterpret_cast<u16x4*>(&As[row * 72 + k]) = o;
    }
#pragma unroll
    for (int i = 0; i < 4; i++) {
      const int row = i * 32 + (t >> 3), k = (t & 7) * 8;
      const u16x8 v = *reinterpret_cast<const u16x8*>(&BT[(size_t)(n0 + row) * 512 + kt + k]);
      *reinterpret_cast<u16x8*>(&Bs[row * 72 + k]) = v;
    }
    __syncthreads();
#pragma unroll
    for (int kk = 0; kk < 2; kk++) {
      bf16x8 a[4], b[4];
#pragma unroll
      for (int mf = 0; mf < 4; mf++)
        a[mf] = *reinterpret_cast<const bf16x8*>(&As[(wm * 64 + mf * 16 + li) * 72 + kk * 32 + lg * 8]);
#pragma unroll
      for (int nf = 0; nf < 4; nf++)
        b[nf] = *reinterpret_cast<const bf16x8*>(&Bs[(wn * 64 + nf * 16 + li) * 72 + kk * 32 + lg * 8]);
#pragma unroll
      for (int mf = 0; mf < 4; mf++)
#pragma unroll
        for (int nf = 0; nf < 4; nf++)
          acc[mf][nf] = MFMA16(a[mf], b[nf], acc[mf][nf]);
    }
    __syncthreads();
  }
  const int lg4 = lg * 4;
#pragma unroll
  for (int nf = 0; nf < 4; nf++) {
    const int col = n0 + wn * 64 + nf * 16 + li;
#pragma unroll
    for (int mf = 0; mf < 4; mf++) {
      const int row = m0 + wm * 64 + mf * 16 + lg4;
#pragma unroll
      for (int r = 0; r < 4; r++)
        out[(size_t)col * 512 + row + r] = f2bf_bits(acc[mf][nf][r] * scale);
    }
  }
}

// ---------------------------------------------------------------------------
// Pipeline sync macros.
// ---------------------------------------------------------------------------
#define WAITV(n)                                            \
  {                                                         \
    asm volatile("s_waitcnt vmcnt(" #n ")" ::: "memory");   \
    __builtin_amdgcn_sched_barrier(0);                      \
  }
#define WAITLGKM()                                          \
  {                                                         \
    asm volatile("s_waitcnt lgkmcnt(0)" ::: "memory");      \
    __builtin_amdgcn_sched_barrier(0);                      \
  }
#define BAR3()                                              \
  {                                                         \
    __builtin_amdgcn_s_barrier();                           \
    __builtin_amdgcn_sched_barrier(0);                      \
  }

// ---------------------------------------------------------------------------
// gemm_hyb_body: fp32 A -> regs -> cvt -> lane-linear ds_write_b128 into
// R7's exact LDS image (slot^((row>>1)&3) involution, proven 0-conflict
// reads); B via global_load_lds, triple-buffered, counted vmcnt(2).
// 128x128 tile, BK=32, K=512 (16 steps), 40KB LDS -> 4 blocks/CU.
// Steady invariant before WAITV(2): outstanding = [B(t+1), A(t+2)regs... ]
// no -- per iter issue order is A(t+2)x4 then B(t+2)x2; WAITV(2) drains
// B(t)+A(t+1), leaves B(t+1) in flight across both barriers.
// ---------------------------------------------------------------------------
__device__ __forceinline__ void gemm_hyb_body(
    const float* __restrict__ A, const unsigned short* __restrict__ BT,
    const float* __restrict__ bias, unsigned short* __restrict__ out,
    int Ntiles, int ldc, int wg) {
  __shared__ __align__(16) unsigned short As[2][128 * 32];  // 16 KB
  __shared__ __align__(16) unsigned short Bs[3][128 * 32];  // 24 KB
  const int t = threadIdx.x;
  const int w = t >> 6, l = t & 63, li = l & 15, lg = l >> 4;
  const int wm = w >> 1, wn = w & 1;
  const int m0 = (wg / Ntiles) * 128, n0 = (wg % Ntiles) * 128;

  f32x4 acc[4][4] = {};
  float4 ra[2][2];  // [i][half]: row i*64+(t>>2), 8 floats at slot*8
  const int rrow = t >> 2;
  const int slot = (t & 3) ^ ((t >> 3) & 3);  // == (t&3) ^ ((row>>1)&3), i-indep
  const float* aptr = A + (size_t)(m0 + rrow) * 512 + slot * 8;

#define ISSUE_A(kt)                                                            \
  {                                                                            \
    ra[0][0] = *reinterpret_cast<const float4*>(aptr + (kt));                  \
    ra[0][1] = *reinterpret_cast<const float4*>(aptr + (kt) + 4);              \
    ra[1][0] = *reinterpret_cast<const float4*>(aptr + 64 * 512 + (kt));       \
    ra[1][1] = *reinterpret_cast<const float4*>(aptr + 64 * 512 + (kt) + 4);   \
  }

#define CVT_WRITE_A(buf)                                                       \
  {                                                                            \
    _Pragma("unroll") for (int i = 0; i < 2; i++) {                            \
      bf16x8 v;                                                                \
      _Pragma("unroll") for (int j = 0; j < 4; j++) {                          \
        v[j] = (__bf16)ra[i][0][j];                                            \
        v[j + 4] = (__bf16)ra[i][1][j];                                        \
      }                                                                        \
      *reinterpret_cast<bf16x8*>(&As[buf][(i * 256 + t) * 8]) = v;             \
    }                                                                          \
  }

#define STAGE_B(tile)                                                          \
  {                                                                            \
    const int bb = (tile) % 3;                                                 \
    const int kt = (tile) * 32;                                                \
    _Pragma("unroll") for (int i = 0; i < 2; i++) {                            \
      const int row = i * 64 + rrow;                                           \
      gload16(&BT[(size_t)(n0 + row) * 512 + kt + slot * 8],                   \
              &Bs[bb][(i * 256 + t) * 8]);                                     \
    }                                                                          \
  }

#define COMPUTE(tile)                                                          \
  {                                                                            \
    const int ab = (tile) & 1;                                                 \
    const int bb = (tile) % 3;                                                 \
    bf16x8 a[4], b[4];                                                         \
    _Pragma("unroll") for (int mf = 0; mf < 4; mf++) {                         \
      const int r = wm * 64 + mf * 16 + li;                                    \
      a[mf] = *reinterpret_cast<const bf16x8*>(                                \
          &As[ab][r * 32 + ((lg ^ ((r >> 1) & 3)) * 8)]);                      \
    }                                                                          \
    _Pragma("unroll") for (int nf = 0; nf < 4; nf++) {                         \
      const int r = wn * 64 + nf * 16 + li;                                    \
      b[nf] = *reinterpret_cast<const bf16x8*>(                                \
          &Bs[bb][r * 32 + ((lg ^ ((r >> 1) & 3)) * 8)]);                      \
    }                                                                          \
    _Pragma("unroll") for (int mf = 0; mf < 4; mf++)                           \
        _Pragma("unroll") for (int nf = 0; nf < 4; nf++)                       \
            acc[mf][nf] = MFMA16(a[mf], b[nf], acc[mf][nf]);                   \
  }

  // ---- prologue ----
  ISSUE_A(0);      // 4 loads (tile 0)
  STAGE_B(0);      // 2 DMA
  STAGE_B(1);      // 2 DMA
  WAITV(4);        // drain A(0); B(0),B(1) stay in flight
  CVT_WRITE_A(0);  // tile 0 -> As[0]
  ISSUE_A(32);     // tile 1 -> regs

#pragma unroll 1
  for (int tt = 0; tt < 15; ++tt) {
    WAITV(2);                     // drain B(tt) + A-regs(tt+1); B(tt+1) flies
    CVT_WRITE_A((tt + 1) & 1);    // tile tt+1 -> As[(tt+1)&1]
    if (tt < 14) {
      ISSUE_A((tt + 2) * 32);     // tile tt+2 -> regs (issued AFTER cvt)
      STAGE_B(tt + 2);            // tile tt+2 -> Bs[(tt+2)%3]
    }
    WAITLGKM();                   // ds_writes complete before publish
    BAR3();                       // publish As[tt+1]; all waves' B(tt) drained
    COMPUTE(tt);
    BAR3();                       // frees As[tt&1], Bs[tt%3]
  }
  // tt=15: B(15) still in flight per-wave; drain + publish
  WAITV(0);
  BAR3();
  COMPUTE(15);

#undef ISSUE_A
#undef CVT_WRITE_A
#undef STAGE_B
#undef COMPUTE

  const int lg4 = lg * 4;
#pragma unroll
  for (int nf = 0; nf < 4; nf++) {
    const int col = n0 + wn * 64 + nf * 16 + li;
    const float bv = bias[col];
#pragma unroll
    for (int mf = 0; mf < 4; mf++) {
      const int row = m0 + wm * 64 + mf * 16 + lg4;
#pragma unroll
      for (int r = 0; r < 4; r++)
        out[(size_t)(row + r) * ldc + col] = f2bf_bits(acc[mf][nf][r] + bv);
    }
  }
}

// Merged q + pkv + pq projections.  grid 6176 (2048 q | 4096 pkv | 32 pq).
__global__ __launch_bounds__(256, 4) void gemm_hyb_qpkv(
    const float* query, const float* context, const float* pquery,
    const unsigned short* WqeT, const unsigned short* WpkveT,
    const unsigned short* WpqeT, const float* bqe, const float* bpkve,
    const float* bpqe, unsigned short* q_buf, unsigned short* pkv_buf,
    unsigned short* pq_buf) {
  const int q8 = gridDim.x >> 3;
  int wg = ((int)blockIdx.x & 7) * q8 + ((int)blockIdx.x >> 3);
  const float* A;
  const unsigned short* BT;
  const float* bias;
  unsigned short* out;
  int Ntiles, ldc;
  if (wg < 2048) {
    A = query; BT = WqeT; bias = bqe; out = q_buf; Ntiles = 4; ldc = 512;
  } else if (wg < 6144) {
    wg -= 2048; A = context; BT = WpkveT; bias = bpkve; out = pkv_buf;
    Ntiles = 8; ldc = 1024;
  } else {
    wg -= 6144; A = pquery; BT = WpqeT; bias = bpqe; out = pq_buf;
    Ntiles = 4; ldc = 512;
  }
  gemm_hyb_body(A, BT, bias, out, Ntiles, ldc, wg);
}

// ---------------------------------------------------------------------------
// gemm3p_body (bf16 A, depth-3, R7-verified) — final projection.
// ---------------------------------------------------------------------------
__device__ __forceinline__ void gemm3p_body_f32out(
    const unsigned short* __restrict__ A, const unsigned short* __restrict__ BT,
    const float* __restrict__ bias, float* __restrict__ out, int Ntiles,
    int ldc, int wg) {
  __shared__ __align__(16) unsigned short As[3][128 * 32];
  __shared__ __align__(16) unsigned short Bs[3][128 * 32];
  const int t = threadIdx.x;
  const int w = t >> 6, l = t & 63, li = l & 15, lg = l >> 4;
  const int wm = w >> 1, wn = w & 1;
  const int m0 = (wg / Ntiles) * 128, n0 = (wg % Ntiles) * 128;

  f32x4 acc[4][4] = {};
  const int srow = t >> 2, sslot = t & 3;

#define STAGE3(tile)                                                           \
  {                                                                            \
    const int bb = (tile) % 3;                                                 \
    const int kt = (tile) * 32;                                                \
    _Pragma("unroll") for (int i = 0; i < 2; i++) {                            \
      const int row = i * 64 + srow;                                           \
      const int gs = (sslot ^ ((row >> 1) & 3)) * 8;                           \
      gload16(&A[(size_t)(m0 + row) * 512 + kt + gs], &As[bb][(i * 256 + t) * 8]); \
    }                                                                          \
    _Pragma("unroll") for (int i = 0; i < 2; i++) {                            \
      const int row = i * 64 + srow;                                           \
      const int gs = (sslot ^ ((row >> 1) & 3)) * 8;                           \
      gload16(&BT[(size_t)(n0 + row) * 512 + kt + gs], &Bs[bb][(i * 256 + t) * 8]); \
    }                                                                          \
  }

#define COMPUTE3(tile)                                                         \
  {                                                                            \
    const int bb = (tile) % 3;                                                 \
    bf16x8 a[4], b[4];                                                         \
    _Pragma("unroll") for (int mf = 0; mf < 4; mf++) {                         \
      const int r = wm * 64 + mf * 16 + li;                                    \
      a[mf] = *reinterpret_cast<const bf16x8*>(                                \
          &As[bb][r * 32 + ((lg ^ ((r >> 1) & 3)) * 8)]);                      \
    }                                                                          \
    _Pragma("unroll") for (int nf = 0; nf < 4; nf++) {                         \
      const int r = wn * 64 + nf * 16 + li;                                    \
      b[nf] = *reinterpret_cast<const bf16x8*>(                                \
          &Bs[bb][r * 32 + ((lg ^ ((r >> 1) & 3)) * 8)]);                      \
    }                                                                          \
    _Pragma("unroll") for (int mf = 0; mf < 4; mf++)                           \
        _Pragma("unroll") for (int nf = 0; nf < 4; nf++)                       \
            acc[mf][nf] = MFMA16(a[mf], b[nf], acc[mf][nf]);                   \
  }

  STAGE3(0);
  STAGE3(1);
  STAGE3(2);

#pragma unroll 1
  for (int tt = 0; tt < 13; ++tt) {
    WAITV(8);
    BAR3();
    COMPUTE3(tt);
    BAR3();
    STAGE3(tt + 3);
  }
  WAITV(8); BAR3(); COMPUTE3(13); BAR3();
  WAITV(4); BAR3(); COMPUTE3(14); BAR3();
  WAITV(0); BAR3(); COMPUTE3(15);

#undef STAGE3
#undef COMPUTE3

  const int lg4 = lg * 4;
#pragma unroll
  for (int nf = 0; nf < 4; nf++) {
    const int col = n0 + wn * 64 + nf * 16 + li;
    const float bv = bias[col];
#pragma unroll
    for (int mf = 0; mf < 4; mf++) {
      const int row = m0 + wm * 64 + mf * 16 + lg4;
#pragma unroll
      for (int r = 0; r < 4; r++)
        out[(size_t)(row + r) * ldc + col] = acc[mf][nf][r] + bv;
    }
  }
}

__global__ __launch_bounds__(256, 3) void gemm3p_final(
    const unsigned short* A, const unsigned short* BT, const float* bias,
    float* out) {
  const int q8 = gridDim.x >> 3;
  const int wg = ((int)blockIdx.x & 7) * q8 + ((int)blockIdx.x >> 3);
  gemm3p_body_f32out(A, BT, bias, out, 4, 512, wg);
}

// ---------------------------------------------------------------------------
// 128x128 bf16 GEMM (1-phase) for the small kv/pc GEMM, N=1536 split output.
// ---------------------------------------------------------------------------
__global__ __launch_bounds__(256) void gemm_kvpc(
    const unsigned short* __restrict__ A, const unsigned short* __restrict__ BT,
    const float* __restrict__ bias0, const float* __restrict__ bias1,
    const float* __restrict__ bias2, unsigned short* out0, unsigned short* out1,
    float* out2, int Ntiles) {
  __shared__ __align__(16) unsigned short As[128 * 64];
  __shared__ __align__(16) unsigned short Bs[128 * 64];
  const int t = threadIdx.x;
  const int w = t >> 6, l = t & 63, li = l & 15, lg = l >> 4;
  const int wm = w >> 1, wn = w & 1;
  const int K = 512;
  const int m0 = (blockIdx.x / Ntiles) * 128, n0 = (blockIdx.x % Ntiles) * 128;

  f32x4 acc[4][4] = {};
  const int sr = t >> 3, sslot = t & 7;

  for (int kt = 0; kt < K; kt += 64) {
#pragma unroll
    for (int i = 0; i < 4; i++) {
      const int row = i * 32 + sr;
      const int gs = (sslot ^ (row & 7)) * 8;
      gload16(&A[(size_t)(m0 + row) * K + kt + gs], &As[(i * 256 + t) * 8]);
      gload16(&BT[(size_t)(n0 + row) * K + kt + gs], &Bs[(i * 256 + t) * 8]);
    }
    __syncthreads();
#pragma unroll
    for (int kk = 0; kk < 2; kk++) {
      bf16x8 a[4], b[4];
#pragma unroll
      for (int mf = 0; mf < 4; mf++) {
        const int r = wm * 64 + mf * 16 + li;
        a[mf] = *reinterpret_cast<const bf16x8*>(&As[r * 64 + (((kk * 4 + lg) ^ (r & 7)) * 8)]);
      }
#pragma unroll
      for (int nf = 0; nf < 4; nf++) {
        const int r = wn * 64 + nf * 16 + li;
        b[nf] = *reinterpret_cast<const bf16x8*>(&Bs[r * 64 + (((kk * 4 + lg) ^ (r & 7)) * 8)]);
      }
#pragma unroll
      for (int mf = 0; mf < 4; mf++)
#pragma unroll
        for (int nf = 0; nf < 4; nf++)
          acc[mf][nf] = MFMA16(a[mf], b[nf], acc[mf][nf]);
    }
    __syncthreads();
  }

  const int lg4 = lg * 4;
#pragma unroll
  for (int nf = 0; nf < 4; nf++) {
    const int col = n0 + wn * 64 + nf * 16 + li;
    if (col < 512) {
      const float bv = bias0[col];
#pragma unroll
      for (int mf = 0; mf < 4; mf++) {
        const int row = m0 + wm * 64 + mf * 16 + lg4;
#pragma unroll
        for (int r = 0; r < 4; r++)
          out0[(size_t)(row + r) * 512 + col] = f2bf_bits(acc[mf][nf][r] + bv);
      }
    } else if (col < 1024) {
      const float bv = bias1[col - 512];
#pragma unroll
      for (int mf = 0; mf < 4; mf++) {
        const int row = m0 + wm * 64 + mf * 16 + lg4;
#pragma unroll
        for (int r = 0; r < 4; r++)
          out1[(size_t)(row + r) * 512 + col - 512] = f2bf_bits(acc[mf][nf][r] + bv);
      }
    } else {
      const float bv = bias2[col - 1024];
#pragma unroll
      for (int mf = 0; mf < 4; mf++) {
        const int row = m0 + wm * 64 + mf * 16 + lg4;
#pragma unroll
        for (int r = 0; r < 4; r++)
          out2[(size_t)(row + r) * 512 + col - 1024] = acc[mf][nf][r] + bv;
      }
    }
  }
}

// ---------------------------------------------------------------------------
// Pack attention, split over S. grid (128 bh, 8 chunks), block 256 (4 waves).
// ---------------------------------------------------------------------------
__global__ __launch_bounds__(256) void pack_attn(
    const unsigned short* __restrict__ pq_buf,
    const unsigned short* __restrict__ pkv_buf, float* __restrict__ partial) {
  __shared__ __align__(16) unsigned short pkL[64 * 72];
  __shared__ __align__(16) unsigned short pvT[64 * 72];
  __shared__ __align__(16) unsigned short prL[4 * 16 * 72];
  const int t = threadIdx.x, w = t >> 6, l = t & 63, li = l & 15, lg = l >> 4;
  const int bh = blockIdx.x, b = bh >> 3, h = bh & 7;
  const int sb = blockIdx.y * 512;

  bf16x8 aq[2];
  {
    const size_t base = ((size_t)(b * 64 + w * 16 + li)) * 512 + h * 64;
    aq[0] = *reinterpret_cast<const bf16x8*>(&pq_buf[base + lg * 8]);
    aq[1] = *reinterpret_cast<const bf16x8*>(&pq_buf[base + 32 + lg * 8]);
  }

  f32x4 acc[4] = {};
  float lsum[4] = {};

  for (int st = 0; st < 8; st++) {
    const int s0 = sb + st * 64;
#pragma unroll
    for (int i = 0; i < 2; i++) {
      const int row = i * 32 + (t >> 3), c = (t & 7) * 8;
      const u16x8 v = *reinterpret_cast<const u16x8*>(
          &pkv_buf[((size_t)(b * 4096 + s0 + row)) * 1024 + h * 64 + c]);
      *reinterpret_cast<u16x8*>(&pkL[row * 72 + c]) = v;
    }
    {
      const int rp = t >> 3, c = (t & 7) * 8;
      const size_t base = ((size_t)(b * 4096 + s0 + 2 * rp)) * 1024 + 512 + h * 64 + c;
      const u16x8 u0 = *reinterpret_cast<const u16x8*>(&pkv_buf[base]);
      const u16x8 u1 = *reinterpret_cast<const u16x8*>(&pkv_buf[base + 1024]);
#pragma unroll
      for (int j = 0; j < 8; j++) {
        const int val = ((int)u0[j] & 0xffff) | ((int)u1[j] << 16);
        *reinterpret_cast<int*>(&pvT[(c + j) * 72 + 2 * rp]) = val;
      }
    }
    __syncthreads();
    f32x4 sc[4] = {};
#pragma unroll
    for (int nf = 0; nf < 4; nf++) {
#pragma unroll
      for (int kk = 0; kk < 2; kk++) {
        const bf16x8 bk = *reinterpret_cast<const bf16x8*>(
            &pkL[(nf * 16 + li) * 72 + kk * 32 + lg * 8]);
        sc[nf] = MFMA16(aq[kk], bk, sc[nf]);
      }
    }
#pragma unroll
    for (int nf = 0; nf < 4; nf++) {
#pragma unroll
      for (int r = 0; r < 4; r++) {
        const float e = __expf(sc[nf][r]);
        lsum[r] += e;
        prL[(w * 16 + lg * 4 + r) * 72 + nf * 16 + li] = f2bf_bits(e);
      }
    }
#pragma unroll
    for (int kk = 0; kk < 2; kk++) {
      const bf16x8 ap = *reinterpret_cast<const bf16x8*>(
          &prL[(w * 16 + li) * 72 + kk * 32 + lg * 8]);
#pragma unroll
      for (int nf = 0; nf < 4; nf++) {
        const bf16x8 bv = *reinterpret_cast<const bf16x8*>(
            &pvT[(nf * 16 + li) * 72 + kk * 32 + lg * 8]);
        acc[nf] = MFMA16(ap, bv, acc[nf]);
      }
    }
    __syncthreads();
  }

#pragma unroll
  for (int m = 1; m < 16; m <<= 1)
#pragma unroll
    for (int r = 0; r < 4; r++) lsum[r] += __shfl_xor(lsum[r], m);

  const size_t pbase = ((size_t)(bh * 8 + blockIdx.y)) * 4160;
#pragma unroll
  for (int nf = 0; nf < 4; nf++)
#pragma unroll
    for (int r = 0; r < 4; r++)
      partial[pbase + (size_t)(w * 16 + lg * 4 + r) * 64 + nf * 16 + li] = acc[nf][r];
  if (li == 0)
#pragma unroll
    for (int r = 0; r < 4; r++) partial[pbase + 4096 + w * 16 + lg * 4 + r] = lsum[r];
}

__global__ __launch_bounds__(256) void pack_combine(const float* __restrict__ partial,
                                                    unsigned short* __restrict__ pc_buf) {
  const int bh = blockIdx.x, b = bh >> 3, h = bh & 7;
  const int t = threadIdx.x;
#pragma unroll
  for (int e = 0; e < 16; e++) {
    const int idx = e * 256 + t;
    const int p = idx >> 6, d = idx & 63;
    float s = 0.f, den = 0.f;
#pragma unroll
    for (int c = 0; c < 8; c++) {
      const float* pb = &partial[((size_t)(bh * 8 + c)) * 4160];
      s += pb[idx];
      den += pb[4096 + p];
    }
    pc_buf[((size_t)(b * 64 + p)) * 512 + h * 64 + d] = f2bf_bits(s / den);
  }
}

// ---------------------------------------------------------------------------
// Unpack attention. grid (16 s-tiles, 128 bh), block 256 (4 waves x 64 s-rows).
// ---------------------------------------------------------------------------
__global__ __launch_bounds__(256) void unpack_attn(
    const unsigned short* q_in, const unsigned short* __restrict__ k_buf,
    const unsigned short* __restrict__ v_buf, float* __restrict__ aw_out,
    unsigned short* attnh_out) {
  __shared__ __align__(16) unsigned short kL[64 * 72];
  __shared__ __align__(16) unsigned short vT[64 * 72];
  __shared__ __align__(16) unsigned short prL[4 * 64 * 72];
  const int t = threadIdx.x, w = t >> 6, l = t & 63, li = l & 15, lg = l >> 4;
  const int bh = blockIdx.y, b = bh >> 3, h = bh & 7;
  const int sbase = blockIdx.x * 256 + w * 64;

#pragma unroll
  for (int i = 0; i < 2; i++) {
    const int p = i * 32 + (t >> 3), c = (t & 7) * 8;
    const u16x8 v = *reinterpret_cast<const u16x8*>(
        &k_buf[((size_t)(b * 64 + p)) * 512 + h * 64 + c]);
    *reinterpret_cast<u16x8*>(&kL[p * 72 + c]) = v;
  }
  {
    const int rp = t >> 3, c = (t & 7) * 8;
    const size_t base = ((size_t)(b * 64 + 2 * rp)) * 512 + h * 64 + c;
    const u16x8 u0 = *reinterpret_cast<const u16x8*>(&v_buf[base]);
    const u16x8 u1 = *reinterpret_cast<const u16x8*>(&v_buf[base + 512]);
#pragma unroll
    for (int j = 0; j < 8; j++) {
      const int val = ((int)u0[j] & 0xffff) | ((int)u1[j] << 16);
      *reinterpret_cast<int*>(&vT[(c + j) * 72 + 2 * rp]) = val;
    }
  }
  bf16x8 aq[4][2];
#pragma unroll
  for (int mf = 0; mf < 4; mf++) {
    const size_t base = ((size_t)(b * 4096 + sbase + mf * 16 + li)) * 512 + h * 64;
    aq[mf][0] = *reinterpret_cast<const bf16x8*>(&q_in[base + lg * 8]);
    aq[mf][1] = *reinterpret_cast<const bf16x8*>(&q_in[base + 32 + lg * 8]);
  }
  __syncthreads();

  f32x4 sc[4][4] = {};
#pragma unroll
  for (int kk = 0; kk < 2; kk++)
#pragma unroll
    for (int nf = 0; nf < 4; nf++) {
      const bf16x8 bk = *reinterpret_cast<const bf16x8*>(
          &kL[(nf * 16 + li) * 72 + kk * 32 + lg * 8]);
#pragma unroll
      for (int mf = 0; mf < 4; mf++) sc[mf][nf] = MFMA16(aq[mf][kk], bk, sc[mf][nf]);
    }

#pragma unroll
  for (int mf = 0; mf < 4; mf++) {
#pragma unroll
    for (int r = 0; r < 4; r++) {
      float e[4];
      float rs = 0.f;
#pragma unroll
      for (int nf = 0; nf < 4; nf++) {
        e[nf] = __expf(sc[mf][nf][r]);
        rs += e[nf];
      }
#pragma unroll
      for (int m = 1; m < 16; m <<= 1) rs += __shfl_xor(rs, m);
      const float inv = 1.0f / rs;
      const int srow = sbase + mf * 16 + lg * 4 + r;
#pragma unroll
      for (int nf = 0; nf < 4; nf++) {
        const float pr = e[nf] * inv;
        aw_out[(size_t)srow * 8192 + bh * 64 + nf * 16 + li] = pr;
        prL[(w * 64 + mf * 16 + lg * 4 + r) * 72 + nf * 16 + li] = f2bf_bits(pr);
      }
    }
  }

  f32x4 acc[4][4] = {};
#pragma unroll
  for (int kk = 0; kk < 2; kk++)
#pragma unroll
    for (int mf = 0; mf < 4; mf++) {
      const bf16x8 ap = *reinterpret_cast<const bf16x8*>(
          &prL[(w * 64 + mf * 16 + li) * 72 + kk * 32 + lg * 8]);
#pragma unroll
      for (int nf = 0; nf < 4; nf++) {
        const bf16x8 bv = *reinterpret_cast<const bf16x8*>(
            &vT[(nf * 16 + li) * 72 + kk * 32 + lg * 8]);
        acc[mf][nf] = MFMA16(ap, bv, acc[mf][nf]);
      }
    }
#pragma unroll
  for (int mf = 0; mf < 4; mf++)
#pragma unroll
    for (int nf = 0; nf < 4; nf++)
#pragma unroll
      for (int r = 0; r < 4; r++)
        attnh_out[((size_t)(b * 4096 + sbase + mf * 16 + lg * 4 + r)) * 512 + h * 64 +
                  nf * 16 + li] = f2bf_bits(acc[mf][nf][r]);
}

// ---------------------------------------------------------------------------
extern "C" void kernel_launch(void* const* d_in, const int* in_sizes, int n_in,
                              void* d_out, int out_size, void* d_ws, size_t ws_size,
                              hipStream_t stream) {
  (void)in_sizes; (void)n_in; (void)out_size; (void)ws_size;

  const float* query   = (const float*)d_in[0];
  const float* pquery  = (const float*)d_in[1];
  const float* context = (const float*)d_in[2];
  const float* Wi  = (const float*)d_in[3];  const float* bi  = (const float*)d_in[4];
  const float* Wip = (const float*)d_in[5];  const float* bip = (const float*)d_in[6];
  const float* Wic = (const float*)d_in[7];  const float* bic = (const float*)d_in[8];
  const float* Wq  = (const float*)d_in[9];  const float* bq  = (const float*)d_in[10];
  const float* Wpq = (const float*)d_in[11]; const float* bpq = (const float*)d_in[12];
  const float* Wk  = (const float*)d_in[13]; const float* bk  = (const float*)d_in[14];
  const float* Wpk = (const float*)d_in[15]; const float* bpk = (const float*)d_in[16];
  const float* Wv  = (const float*)d_in[17]; const float* bv  = (const float*)d_in[18];
  const float* Wpv = (const float*)d_in[19]; const float* bpv = (const float*)d_in[20];
  const float* Wo  = (const float*)d_in[21]; const float* bo  = (const float*)d_in[22];
  const float* Wop = (const float*)d_in[23]; const float* bop = (const float*)d_in[24];

  // ---- workspace layout ----
  char* ws = (char*)d_ws;
  unsigned short* WT     = (unsigned short*)(ws);                 // 8 x 512x512 bf16
  unsigned short* WqeT   = (unsigned short*)(ws + 4u * 1024 * 1024);
  unsigned short* WpqeT  = WqeT + 512 * 512;
  unsigned short* WpkveT = WpqeT + 512 * 512;                     // 1024 x 512
  float* bqe   = (float*)(WpkveT + (size_t)1024 * 512);
  float* bpqe  = bqe + 512;
  float* bpkve = bpqe + 512;
  unsigned short* q_buf   = (unsigned short*)(ws + 8u * 1024 * 1024);  // 65536x512 (later attn_h)
  unsigned short* pkv_buf = q_buf + (size_t)65536 * 512;               // 65536x1024
  unsigned short* pq_buf  = pkv_buf + (size_t)65536 * 1024;
  unsigned short* pc_buf  = pq_buf + (size_t)1024 * 512;
  unsigned short* k_buf   = pc_buf + (size_t)1024 * 512;
  unsigned short* v_buf   = k_buf + (size_t)1024 * 512;
  float* partial = (float*)(v_buf + (size_t)1024 * 512);               // 1024 x 4160 f32

  float* out_attn = (float*)d_out;                       // (B,S,512) fp32
  float* out_pc   = out_attn + (size_t)16 * 4096 * 512;  // (B,P,512)
  float* out_aw   = out_pc + (size_t)16 * 64 * 512;      // (S,B*H,P)

  const dim3 blk(256);

  // 1) weight prep
  Ptr8 tsrc; tsrc.p[0]=Wq; tsrc.p[1]=Wpq; tsrc.p[2]=Wpk; tsrc.p[3]=Wpv;
  tsrc.p[4]=Wk; tsrc.p[5]=Wv; tsrc.p[6]=Wop; tsrc.p[7]=Wo;
  prep_kernel<<<dim3(16, 16, 9), blk, 0, stream>>>(
      tsrc, WT, bi, bip, bic, Wq, Wpq, Wpk, Wpv, bq, bpq, bpk, bpv, bqe);
  gemm_wcomb<<<dim3(4, 4, 4), blk, 0, stream>>>(Wi, Wip, Wic, WT, WqeT);

  // 2) all input projections in ONE launch (fp32 A -> reg -> cvt -> ds_write)
  gemm_hyb_qpkv<<<dim3(6176), blk, 0, stream>>>(
      query, context, pquery, WqeT, WpkveT, WpqeT, bqe, bpkve, bpqe,
      q_buf, pkv_buf, pq_buf);

  // 3) pack attention (8 chunks) + combine -> pc
  pack_attn<<<dim3(128, 8), blk, 0, stream>>>(pq_buf, pkv_buf, partial);
  pack_combine<<<128, blk, 0, stream>>>(partial, pc_buf);

  // 4) k, v, pc_out (fused N=1536)
  gemm_kvpc<<<dim3(96), blk, 0, stream>>>(
      pc_buf, WT + (size_t)4 * 262144, bk, bv, bop, k_buf, v_buf, out_pc, 12);

  // 5) unpack attention: aw_t out + attn_h in-place over q_buf
  unpack_attn<<<dim3(16, 128), blk, 0, stream>>>(q_buf, k_buf, v_buf, out_aw, q_buf);

  // 6) final projection: attn = attn_h @ Wo + bo (bf16 A, depth-3 DMA)
  gemm3p_final<<<dim3(2048), blk, 0, stream>>>(
      q_buf, WT + (size_t)7 * 262144, bo, out_attn);
}